// Round 8
// baseline (1009.196 us; speedup 1.0000x reference)
//
#include <hip/hip_runtime.h>

#define NN 50000
#define NE 400000
#define DD 512
#define NB 196  // ceil(NN/256)

typedef unsigned short u16;
typedef float f32x4 __attribute__((ext_vector_type(4)));
typedef __bf16 bf16x8 __attribute__((ext_vector_type(8)));

__device__ __forceinline__ u16 f2bf(float f) {
  unsigned u = __builtin_bit_cast(unsigned, f);
  unsigned r = (u + 0x7FFFu + ((u >> 16) & 1u)) >> 16;
  return (u16)r;
}
__device__ __forceinline__ float bf_lo(unsigned v) {
  return __builtin_bit_cast(float, v << 16);
}
__device__ __forceinline__ float bf_hi(unsigned v) {
  return __builtin_bit_cast(float, v & 0xffff0000u);
}

__device__ __forceinline__ void gload16(const void* g, void* l) {
  __builtin_amdgcn_global_load_lds(
      (const __attribute__((address_space(1))) unsigned int*)g,
      (__attribute__((address_space(3))) unsigned int*)l, 16, 0, 0);
}

// ---------- edge dtype detect ----------
__global__ void k_detect(const long long* __restrict__ p, int* __restrict__ vio) {
  bool bad = false;
  for (int i = blockIdx.x * blockDim.x + threadIdx.x; i < NE; i += blockDim.x * gridDim.x) {
    long long v = p[i];
    bad |= (v < 0 || v >= NN);
  }
  unsigned long long m = __ballot(bad);
  if (m != 0ull && (threadIdx.x & 63) == 0) atomicOr(vio, 1);
}

// ---------- normalize edges + degree count (fused) ----------
__global__ void k_normcnt(const void* __restrict__ ep, const int* __restrict__ vio,
                          int* __restrict__ src, int* __restrict__ dst,
                          int* __restrict__ deg) {
  bool is64 = (*vio == 0);
  for (int e = blockIdx.x * blockDim.x + threadIdx.x; e < NE; e += blockDim.x * gridDim.x) {
    int s_, d_;
    if (is64) {
      const long long* p = (const long long*)ep;
      s_ = (int)p[e];
      d_ = (int)p[NE + e];
    } else {
      const int* p = (const int*)ep;
      s_ = p[e];
      d_ = p[NE + e];
    }
    src[e] = s_;
    dst[e] = d_;
    atomicAdd(&deg[d_], 1);
  }
}

// ---------- scan / CSR ----------
__global__ void k_scan1(const int* __restrict__ deg, int* __restrict__ offs,
                        int* __restrict__ bsums) {
  __shared__ int sm[256];
  int t = threadIdx.x, i = blockIdx.x * 256 + t;
  int v = (i < NN) ? deg[i] : 0;
  sm[t] = v;
  __syncthreads();
  int x = v;
  for (int d = 1; d < 256; d <<= 1) {
    int y = (t >= d) ? sm[t - d] : 0;
    __syncthreads();
    x += y;
    sm[t] = x;
    __syncthreads();
  }
  if (i < NN) offs[i + 1] = x;
  if (t == 255) bsums[blockIdx.x] = x;
}

__global__ void k_scan2(const int* __restrict__ bsums, int* __restrict__ boffs) {
  __shared__ int sm[256];
  int t = threadIdx.x;
  int v = (t < NB) ? bsums[t] : 0;
  sm[t] = v;
  __syncthreads();
  int x = v;
  for (int d = 1; d < 256; d <<= 1) {
    int y = (t >= d) ? sm[t - d] : 0;
    __syncthreads();
    x += y;
    sm[t] = x;
    __syncthreads();
  }
  if (t < NB) boffs[t] = x - v;  // exclusive
}

__global__ void k_scan3(int* __restrict__ offs, const int* __restrict__ boffs,
                        const int* __restrict__ deg, float* __restrict__ invd) {
  int i = blockIdx.x * 256 + threadIdx.x;
  if (i == 0) offs[0] = 0;
  if (i < NN) {
    offs[i + 1] += boffs[i >> 8];
    int dg = deg[i];
    if (dg < 1) dg = 1;
    invd[i] = 1.0f / (float)dg;
  }
}

__global__ void k_fill(const int* __restrict__ src, const int* __restrict__ dst,
                       const int* __restrict__ offs, int* __restrict__ cursor,
                       int* __restrict__ csr) {
  int e = blockIdx.x * 256 + threadIdx.x;
  if (e < NE) {
    int d = dst[e];
    int p = atomicAdd(&cursor[d], 1);
    csr[offs[d] + p] = src[e];
  }
}

// ---------- all-6 weight transpose + bf16 convert (one dispatch) ----------
__global__ void k_wt6(const float* __restrict__ W0, const float* __restrict__ W1,
                      const float* __restrict__ W2, const float* __restrict__ W3,
                      const float* __restrict__ W4, const float* __restrict__ W5,
                      u16* __restrict__ wt) {
  __shared__ float t[32][33];
  const float* W;
  switch (blockIdx.z) {
    case 0: W = W0; break;
    case 1: W = W1; break;
    case 2: W = W2; break;
    case 3: W = W3; break;
    case 4: W = W4; break;
    default: W = W5; break;
  }
  u16* Wt = wt + (size_t)blockIdx.z * DD * DD;
  int tx = threadIdx.x & 31, ty = threadIdx.x >> 5;  // 32x8
  int bx = blockIdx.x, by = blockIdx.y;
#pragma unroll
  for (int i = 0; i < 32; i += 8)
    t[ty + i][tx] = W[(size_t)(bx * 32 + ty + i) * DD + by * 32 + tx];
  __syncthreads();
#pragma unroll
  for (int i = 0; i < 32; i += 8)
    Wt[(size_t)(by * 32 + ty + i) * DD + bx * 32 + tx] = f2bf(t[tx][ty + i]);
}

// ---------- x f32 -> bf16 ----------
__global__ void k_cvt(const float* __restrict__ x, u16* __restrict__ xb) {
  size_t i = (size_t)(blockIdx.x * 256 + threadIdx.x) * 8;
  float4 a = *(const float4*)(x + i);
  float4 b = *(const float4*)(x + i + 4);
  uint4 o;
  o.x = (unsigned)f2bf(a.x) | ((unsigned)f2bf(a.y) << 16);
  o.y = (unsigned)f2bf(a.z) | ((unsigned)f2bf(a.w) << 16);
  o.z = (unsigned)f2bf(b.x) | ((unsigned)f2bf(b.y) << 16);
  o.w = (unsigned)f2bf(b.z) | ((unsigned)f2bf(b.w) << 16);
  *(uint4*)(xb + i) = o;
}

// ---------- aggregation: L2-blocked column slices, XCD-pinned ----------
// 16 col-blocks x 32 cols; per col-block the gathered slice = 50000*32*2B =
// 3.2MB -> fits one XCD's 4MB L2. Grid 4096: cb = (bid&7) + 8*(bid>>11), so
// all row-chunks of a col-block land on one XCD (round-robin dispatch
// heuristic, validated by GEMM XCD swizzle R1->R2). Wave = 4 lane-groups of
// 16; group g handles edge j0+g (64B slice = 16 lanes x 4B); shfl-reduce
// across groups; lanes 0-15 write 64B.
__global__ __launch_bounds__(256) void k_agg(const u16* __restrict__ xb,
                                             const int* __restrict__ offs,
                                             const int* __restrict__ csr,
                                             const float* __restrict__ invd,
                                             u16* __restrict__ agg) {
  int bid = blockIdx.x;
  int cb = (bid & 7) + ((bid >> 11) << 3);  // col-block 0..15
  int chunk = (bid >> 3) & 255;             // row-chunk 0..255
  int wid = threadIdx.x >> 6;
  int lane = threadIdx.x & 63;
  int g = lane >> 4;    // group 0..3
  int gl = lane & 15;   // lane in group
  int colOff = cb * 32 + gl * 2;

  int nodeBase = chunk * 196 + wid * 49;
#pragma unroll 1
  for (int i = 0; i < 49; ++i) {
    int n = nodeBase + i;
    if (n >= NN) break;
    int s = offs[n], e = offs[n + 1];
    float a0 = 0.f, a1 = 0.f;
    for (int j0 = s; j0 < e; j0 += 4) {
      int j = j0 + g;
      if (j < e) {
        int u = csr[j];
        unsigned v = *(const unsigned*)(xb + (size_t)u * DD + colOff);
        a0 += bf_lo(v);
        a1 += bf_hi(v);
      }
    }
    a0 += __shfl_down(a0, 32);
    a1 += __shfl_down(a1, 32);
    a0 += __shfl_down(a0, 16);
    a1 += __shfl_down(a1, 16);
    if (lane < 16) {
      float sc = invd[n];
      unsigned o = (unsigned)f2bf(a0 * sc) | ((unsigned)f2bf(a1 * sc) << 16);
      *(unsigned*)(agg + (size_t)n * DD + cb * 32 + lane * 2) = o;
    }
  }
}

// ---------- fused GEMM: C = relu?(Agg@Wl + X@Wr + b) ----------
// R4 structure (best measured: 90us): BM=128, BN=128, BK=64, 4 waves (2x2),
// 2-deep counted-vmcnt pipeline: prologue stages tiles 0,1; each iter waits
// vmcnt(8), raw s_barrier, compute, raw s_barrier, stage(t+2). vmcnt never
// drains to 0 in the main loop. XOR-swizzled LDS (0 conflicts), XCD-bijective
// grid swizzle, setprio around MFMAs, LDS-staged coalesced bf16 epilogue.
__global__ __launch_bounds__(256) void k_gemm(const u16* __restrict__ Aagg,
                                              const u16* __restrict__ Ax,
                                              const u16* __restrict__ Wlt,
                                              const u16* __restrict__ Wrt,
                                              const float* __restrict__ bias,
                                              u16* __restrict__ ybf,
                                              float* __restrict__ yf,
                                              int do_relu) {
  // A0 [0,8192) A1 [8192,16384) B0 [16384,24576) B1 [24576,32768)  (u16 idx)
  __shared__ u16 sh[32768] __attribute__((aligned(16)));

  int tid = threadIdx.x;
  int w = tid >> 6, lane = tid & 63;
  int wr = w >> 1, wc = w & 1;
  int lr = lane & 15;
  int hi = lane >> 4;  // 0..3

  // XCD-bijective decode: same rowTile's 4 colTiles land consecutively on one XCD
  int lin = blockIdx.x;
  int xcd = lin & 7;
  int t = lin >> 3;
  int colT = t & 3;
  int rowT = (t >> 2) * 8 + xcd;  // 0..391
  int blockRow = rowT * 128;
  int nbase = colT * 128;

  // staging source pre-swizzle: LDS granule (row, posg) holds global granule posg^(row&7)
  int srow = lane >> 3;                 // row-within-segment 0..7 (== destRow&7)
  int scol = ((lane & 7) ^ srow) << 3;  // swizzled source column (elements)

  f32x4 acc[4][4];
#pragma unroll
  for (int m = 0; m < 4; ++m)
#pragma unroll
    for (int n = 0; n < 4; ++n) acc[m][n] = (f32x4){0.f, 0.f, 0.f, 0.f};

  // stage K-tile kt (0..15) into buffer b: 8 gload16 per thread
  auto stage = [&](int kt, int b) {
    const u16* Ap = (kt < 8) ? Aagg : Ax;
    const u16* Bp = (kt < 8) ? Wlt : Wrt;
    int kb = (kt & 7) << 6;
    u16* Ad = sh + b * 8192;
    u16* Bd = sh + 16384 + b * 8192;
#pragma unroll
    for (int i = 0; i < 4; ++i) {
      int s = (w << 2) + i;
      int ar = blockRow + s * 8 + srow;
      if (ar > NN - 1) ar = NN - 1;
      int br = nbase + s * 8 + srow;
      gload16(Ap + (size_t)ar * DD + kb + scol, Ad + s * 512);
      gload16(Bp + (size_t)br * DD + kb + scol, Bd + s * 512);
    }
  };

  auto compute = [&](int cur) {
    const u16* As = sh + cur * 8192;
    const u16* Bs = sh + 16384 + cur * 8192;
#pragma unroll
    for (int k2 = 0; k2 < 2; ++k2) {
      int gA = (k2 << 2) + hi;  // wanted k-granule 0..7
      bf16x8 af[4], bfr[4];
#pragma unroll
      for (int m = 0; m < 4; ++m) {
        int r = wr * 64 + m * 16 + lr;
        af[m] = *(const bf16x8*)(As + r * 64 + ((gA ^ (r & 7)) << 3));
      }
#pragma unroll
      for (int n = 0; n < 4; ++n) {
        int r = wc * 64 + n * 16 + lr;
        bfr[n] = *(const bf16x8*)(Bs + r * 64 + ((gA ^ (r & 7)) << 3));
      }
      __builtin_amdgcn_s_setprio(1);
#pragma unroll
      for (int m = 0; m < 4; ++m)
#pragma unroll
        for (int n = 0; n < 4; ++n)
          acc[m][n] = __builtin_amdgcn_mfma_f32_16x16x32_bf16(af[m], bfr[n], acc[m][n], 0, 0, 0);
      __builtin_amdgcn_s_setprio(0);
    }
  };

  stage(0, 0);
  stage(1, 1);  // 16 loads outstanding

  for (int kt = 0; kt < 15; ++kt) {
    int cur = kt & 1;
    // tile kt's 8 loads done; tile kt+1's 8 remain in flight
    asm volatile("s_waitcnt vmcnt(8)" ::: "memory");
    __builtin_amdgcn_s_barrier();
    compute(cur);
    __builtin_amdgcn_s_barrier();  // all waves done reading buf cur
    if (kt + 2 < 16) stage(kt + 2, cur);
  }
  // last tile: only its own 8 loads outstanding -> full drain
  asm volatile("s_waitcnt vmcnt(0)" ::: "memory");
  __builtin_amdgcn_s_barrier();
  compute(1);
  __builtin_amdgcn_s_barrier();

  if (yf) {
    // f32 output (final layer): direct stores
#pragma unroll
    for (int n = 0; n < 4; ++n) {
      int col = nbase + wc * 64 + n * 16 + lr;
      float bv = bias[col];
#pragma unroll
      for (int m = 0; m < 4; ++m) {
        f32x4 v = acc[m][n];
#pragma unroll
        for (int r = 0; r < 4; ++r) {
          int row = blockRow + wr * 64 + m * 16 + hi * 4 + r;
          if (row < NN) {
            float y = v[r] + bv;
            if (do_relu) y = fmaxf(y, 0.f);
            yf[(size_t)row * DD + col] = y;
          }
        }
      }
    }
  } else {
    // bf16 output: stage C tile (128x128 u16 = 32KB in sh[0..16384)) then coalesced writes
#pragma unroll
    for (int n = 0; n < 4; ++n) {
      int col = nbase + wc * 64 + n * 16 + lr;
      float bv = bias[col];
      int g = wc * 8 + n * 2 + (lr >> 3);  // col granule 0..15
#pragma unroll
      for (int m = 0; m < 4; ++m) {
        f32x4 v = acc[m][n];
#pragma unroll
        for (int r = 0; r < 4; ++r) {
          int rl = wr * 64 + m * 16 + hi * 4 + r;
          float y = v[r] + bv;
          if (do_relu) y = fmaxf(y, 0.f);
          sh[rl * 128 + ((g ^ (rl & 15)) << 3) + (lr & 7)] = f2bf(y);
        }
      }
    }
    __syncthreads();
#pragma unroll
    for (int p = 0; p < 8; ++p) {
      int rl = p * 16 + (tid >> 4);
      int gg = tid & 15;
      int grow = blockRow + rl;
      if (grow < NN) {
        uint4 vv = *(const uint4*)(sh + rl * 128 + ((gg ^ (rl & 15)) << 3));
        *(uint4*)(ybf + (size_t)grow * DD + nbase + gg * 8) = vv;
      }
    }
  }
}

extern "C" void kernel_launch(void* const* d_in, const int* in_sizes, int n_in,
                              void* d_out, int out_size, void* d_ws, size_t ws_size,
                              hipStream_t stream) {
  const float* x_in = (const float*)d_in[0];
  const void* eidx = d_in[1];
  const float* Wl[3] = {(const float*)d_in[2], (const float*)d_in[5], (const float*)d_in[8]};
  const float* bl[3] = {(const float*)d_in[3], (const float*)d_in[6], (const float*)d_in[9]};
  const float* Wr[3] = {(const float*)d_in[4], (const float*)d_in[7], (const float*)d_in[10]};

  // workspace layout
  char* w = (char*)d_ws;
  auto alloc = [&](size_t bytes) {
    char* p = w;
    w += (bytes + 255) & ~(size_t)255;
    return p;
  };
  int* vio = (int*)alloc(4);
  int* deg = (int*)alloc((size_t)NN * 4);
  int* cursor = (int*)alloc((size_t)NN * 4);
  int* offs = (int*)alloc((size_t)(NN + 1) * 4);
  int* bsums = (int*)alloc(256 * 4);
  int* boffs = (int*)alloc(256 * 4);
  int* srcA = (int*)alloc((size_t)NE * 4);
  int* dstA = (int*)alloc((size_t)NE * 4);
  int* csr = (int*)alloc((size_t)NE * 4);
  float* invd = (float*)alloc((size_t)NN * 4);
  u16* wt = (u16*)alloc((size_t)6 * DD * DD * 2);
  u16* xb = (u16*)alloc((size_t)NN * DD * 2);
  u16* aggb = (u16*)alloc((size_t)NN * DD * 2);

  u16* wt0l = wt + 0 * DD * DD;
  u16* wt0r = wt + 1 * DD * DD;
  u16* wt1l = wt + 2 * DD * DD;
  u16* wt1r = wt + 3 * DD * DD;
  u16* wt2l = wt + 4 * DD * DD;
  u16* wt2r = wt + 5 * DD * DD;

  u16* dob = (u16*)d_out;  // bf16 scratch inside d_out (layer0 y / layer1 x)

  // zero vio/deg/cursor in one memset (contiguous at ws start)
  size_t zbytes = (size_t)((char*)offs - (char*)vio);
  hipMemsetAsync(vio, 0, zbytes, stream);

  k_detect<<<256, 256, 0, stream>>>((const long long*)eidx, vio);
  k_normcnt<<<512, 256, 0, stream>>>(eidx, vio, srcA, dstA, deg);
  k_scan1<<<NB, 256, 0, stream>>>(deg, offs, bsums);
  k_scan2<<<1, 256, 0, stream>>>(bsums, boffs);
  k_scan3<<<NB, 256, 0, stream>>>(offs, boffs, deg, invd);
  k_fill<<<(NE + 255) / 256, 256, 0, stream>>>(srcA, dstA, offs, cursor, csr);

  k_wt6<<<dim3(16, 16, 6), 256, 0, stream>>>(Wl[0], Wr[0], Wl[1], Wr[1], Wl[2], Wr[2], wt);
  k_cvt<<<(NN * DD / 8 + 255) / 256, 256, 0, stream>>>(x_in, xb);

  const int GEMM_GRID = 1568;  // 392 rowTiles x 4 colTiles, 8-divisible
  const int AGG_GRID = 4096;   // 16 col-blocks x 256 row-chunks
  // layer 0: x = xb, y -> d_out (bf16)
  k_agg<<<AGG_GRID, 256, 0, stream>>>(xb, offs, csr, invd, aggb);
  k_gemm<<<GEMM_GRID, 256, 0, stream>>>(aggb, xb, wt0l, wt0r, bl[0], dob, (float*)nullptr, 1);
  // layer 1: x = d_out (bf16), y -> xb
  k_agg<<<AGG_GRID, 256, 0, stream>>>(dob, offs, csr, invd, aggb);
  k_gemm<<<GEMM_GRID, 256, 0, stream>>>(aggb, dob, wt1l, wt1r, bl[1], xb, (float*)nullptr, 1);
  // layer 2: x = xb, y -> d_out (f32, no relu)
  k_agg<<<AGG_GRID, 256, 0, stream>>>(xb, offs, csr, invd, aggb);
  k_gemm<<<GEMM_GRID, 256, 0, stream>>>(aggb, xb, wt2l, wt2r, bl[2], (u16*)nullptr, (float*)d_out, 0);

  (void)in_sizes; (void)n_in; (void)out_size; (void)ws_size;
}

// Round 9
// 468.263 us; speedup vs baseline: 2.1552x; 2.1552x over previous
//
#include <hip/hip_runtime.h>

#define NN 50000
#define NE 400000
#define DD 512
#define NB 196  // ceil(NN/256)

typedef unsigned short u16;
typedef float f32x4 __attribute__((ext_vector_type(4)));
typedef __bf16 bf16x8 __attribute__((ext_vector_type(8)));

__device__ __forceinline__ u16 f2bf(float f) {
  unsigned u = __builtin_bit_cast(unsigned, f);
  unsigned r = (u + 0x7FFFu + ((u >> 16) & 1u)) >> 16;
  return (u16)r;
}
__device__ __forceinline__ float bf_lo(unsigned v) {
  return __builtin_bit_cast(float, v << 16);
}
__device__ __forceinline__ float bf_hi(unsigned v) {
  return __builtin_bit_cast(float, v & 0xffff0000u);
}

__device__ __forceinline__ void gload16(const void* g, void* l) {
  __builtin_amdgcn_global_load_lds(
      (const __attribute__((address_space(1))) unsigned int*)g,
      (__attribute__((address_space(3))) unsigned int*)l, 16, 0, 0);
}

// ---------- edge dtype detect ----------
__global__ void k_detect(const long long* __restrict__ p, int* __restrict__ vio) {
  bool bad = false;
  for (int i = blockIdx.x * blockDim.x + threadIdx.x; i < NE; i += blockDim.x * gridDim.x) {
    long long v = p[i];
    bad |= (v < 0 || v >= NN);
  }
  unsigned long long m = __ballot(bad);
  if (m != 0ull && (threadIdx.x & 63) == 0) atomicOr(vio, 1);
}

// ---------- normalize edges + degree count (fused) ----------
__global__ void k_normcnt(const void* __restrict__ ep, const int* __restrict__ vio,
                          int* __restrict__ src, int* __restrict__ dst,
                          int* __restrict__ deg) {
  bool is64 = (*vio == 0);
  for (int e = blockIdx.x * blockDim.x + threadIdx.x; e < NE; e += blockDim.x * gridDim.x) {
    int s_, d_;
    if (is64) {
      const long long* p = (const long long*)ep;
      s_ = (int)p[e];
      d_ = (int)p[NE + e];
    } else {
      const int* p = (const int*)ep;
      s_ = p[e];
      d_ = p[NE + e];
    }
    src[e] = s_;
    dst[e] = d_;
    atomicAdd(&deg[d_], 1);
  }
}

// ---------- scan / CSR ----------
__global__ void k_scan1(const int* __restrict__ deg, int* __restrict__ offs,
                        int* __restrict__ bsums) {
  __shared__ int sm[256];
  int t = threadIdx.x, i = blockIdx.x * 256 + t;
  int v = (i < NN) ? deg[i] : 0;
  sm[t] = v;
  __syncthreads();
  int x = v;
  for (int d = 1; d < 256; d <<= 1) {
    int y = (t >= d) ? sm[t - d] : 0;
    __syncthreads();
    x += y;
    sm[t] = x;
    __syncthreads();
  }
  if (i < NN) offs[i + 1] = x;
  if (t == 255) bsums[blockIdx.x] = x;
}

__global__ void k_scan2(const int* __restrict__ bsums, int* __restrict__ boffs) {
  __shared__ int sm[256];
  int t = threadIdx.x;
  int v = (t < NB) ? bsums[t] : 0;
  sm[t] = v;
  __syncthreads();
  int x = v;
  for (int d = 1; d < 256; d <<= 1) {
    int y = (t >= d) ? sm[t - d] : 0;
    __syncthreads();
    x += y;
    sm[t] = x;
    __syncthreads();
  }
  if (t < NB) boffs[t] = x - v;  // exclusive
}

__global__ void k_scan3(int* __restrict__ offs, const int* __restrict__ boffs,
                        const int* __restrict__ deg, float* __restrict__ invd) {
  int i = blockIdx.x * 256 + threadIdx.x;
  if (i == 0) offs[0] = 0;
  if (i < NN) {
    offs[i + 1] += boffs[i >> 8];
    int dg = deg[i];
    if (dg < 1) dg = 1;
    invd[i] = 1.0f / (float)dg;
  }
}

__global__ void k_fill(const int* __restrict__ src, const int* __restrict__ dst,
                       const int* __restrict__ offs, int* __restrict__ cursor,
                       int* __restrict__ csr) {
  int e = blockIdx.x * 256 + threadIdx.x;
  if (e < NE) {
    int d = dst[e];
    int p = atomicAdd(&cursor[d], 1);
    csr[offs[d] + p] = src[e];
  }
}

// ---------- all-6 weight transpose + bf16 convert (one dispatch) ----------
__global__ void k_wt6(const float* __restrict__ W0, const float* __restrict__ W1,
                      const float* __restrict__ W2, const float* __restrict__ W3,
                      const float* __restrict__ W4, const float* __restrict__ W5,
                      u16* __restrict__ wt) {
  __shared__ float t[32][33];
  const float* W;
  switch (blockIdx.z) {
    case 0: W = W0; break;
    case 1: W = W1; break;
    case 2: W = W2; break;
    case 3: W = W3; break;
    case 4: W = W4; break;
    default: W = W5; break;
  }
  u16* Wt = wt + (size_t)blockIdx.z * DD * DD;
  int tx = threadIdx.x & 31, ty = threadIdx.x >> 5;  // 32x8
  int bx = blockIdx.x, by = blockIdx.y;
#pragma unroll
  for (int i = 0; i < 32; i += 8)
    t[ty + i][tx] = W[(size_t)(bx * 32 + ty + i) * DD + by * 32 + tx];
  __syncthreads();
#pragma unroll
  for (int i = 0; i < 32; i += 8)
    Wt[(size_t)(by * 32 + ty + i) * DD + bx * 32 + tx] = f2bf(t[tx][ty + i]);
}

// ---------- x f32 -> bf16 ----------
__global__ void k_cvt(const float* __restrict__ x, u16* __restrict__ xb) {
  size_t i = (size_t)(blockIdx.x * 256 + threadIdx.x) * 8;
  float4 a = *(const float4*)(x + i);
  float4 b = *(const float4*)(x + i + 4);
  uint4 o;
  o.x = (unsigned)f2bf(a.x) | ((unsigned)f2bf(a.y) << 16);
  o.y = (unsigned)f2bf(a.z) | ((unsigned)f2bf(a.w) << 16);
  o.z = (unsigned)f2bf(b.x) | ((unsigned)f2bf(b.y) << 16);
  o.w = (unsigned)f2bf(b.z) | ((unsigned)f2bf(b.w) << 16);
  *(uint4*)(xb + i) = o;
}

#define ACC8(V)                                                     \
  a0 += bf_lo(V.x); a1 += bf_hi(V.x); a2 += bf_lo(V.y); a3 += bf_hi(V.y); \
  a4 += bf_lo(V.z); a5 += bf_hi(V.z); a6 += bf_lo(V.w); a7 += bf_hi(V.w);

// ---------- aggregation: one wave per node, 8-deep load pipeline ----------
// (R7-validated: whole 1KB rows, L3-resident gather; ~55us/dispatch)
__global__ __launch_bounds__(256) void k_agg(const u16* __restrict__ xb,
                                             const int* __restrict__ offs,
                                             const int* __restrict__ csr,
                                             const float* __restrict__ invd,
                                             u16* __restrict__ agg) {
  int node = blockIdx.x * 4 + (threadIdx.x >> 6);
  int lane = threadIdx.x & 63;
  if (node >= NN) return;
  int s = offs[node], e = offs[node + 1];
  float a0 = 0, a1 = 0, a2 = 0, a3 = 0, a4 = 0, a5 = 0, a6 = 0, a7 = 0;
  int j = s;
  for (; j + 8 <= e; j += 8) {
    int u0 = csr[j], u1 = csr[j + 1], u2 = csr[j + 2], u3 = csr[j + 3];
    int u4 = csr[j + 4], u5 = csr[j + 5], u6 = csr[j + 6], u7 = csr[j + 7];
    uint4 v0 = *(const uint4*)(xb + (size_t)u0 * DD + lane * 8);
    uint4 v1 = *(const uint4*)(xb + (size_t)u1 * DD + lane * 8);
    uint4 v2 = *(const uint4*)(xb + (size_t)u2 * DD + lane * 8);
    uint4 v3 = *(const uint4*)(xb + (size_t)u3 * DD + lane * 8);
    uint4 v4 = *(const uint4*)(xb + (size_t)u4 * DD + lane * 8);
    uint4 v5 = *(const uint4*)(xb + (size_t)u5 * DD + lane * 8);
    uint4 v6 = *(const uint4*)(xb + (size_t)u6 * DD + lane * 8);
    uint4 v7 = *(const uint4*)(xb + (size_t)u7 * DD + lane * 8);
    ACC8(v0) ACC8(v1) ACC8(v2) ACC8(v3) ACC8(v4) ACC8(v5) ACC8(v6) ACC8(v7)
  }
  for (; j + 4 <= e; j += 4) {
    int u0 = csr[j], u1 = csr[j + 1], u2 = csr[j + 2], u3 = csr[j + 3];
    uint4 v0 = *(const uint4*)(xb + (size_t)u0 * DD + lane * 8);
    uint4 v1 = *(const uint4*)(xb + (size_t)u1 * DD + lane * 8);
    uint4 v2 = *(const uint4*)(xb + (size_t)u2 * DD + lane * 8);
    uint4 v3 = *(const uint4*)(xb + (size_t)u3 * DD + lane * 8);
    ACC8(v0) ACC8(v1) ACC8(v2) ACC8(v3)
  }
  for (; j < e; ++j) {
    int u = csr[j];
    uint4 v = *(const uint4*)(xb + (size_t)u * DD + lane * 8);
    ACC8(v)
  }
  float sc = invd[node];
  uint4 o;
  o.x = (unsigned)f2bf(a0 * sc) | ((unsigned)f2bf(a1 * sc) << 16);
  o.y = (unsigned)f2bf(a2 * sc) | ((unsigned)f2bf(a3 * sc) << 16);
  o.z = (unsigned)f2bf(a4 * sc) | ((unsigned)f2bf(a5 * sc) << 16);
  o.w = (unsigned)f2bf(a6 * sc) | ((unsigned)f2bf(a7 * sc) << 16);
  *(uint4*)(agg + (size_t)node * DD + lane * 8) = o;
}

// ---------- fused GEMM: C = relu?(Agg@Wl + X@Wr + b) ----------
// R4 structure (best measured: 90us): BM=128, BN=128, BK=64, 4 waves (2x2),
// 2-deep counted-vmcnt pipeline; XOR-swizzled LDS (0 conflicts);
// XCD-bijective grid swizzle; setprio around MFMAs; LDS-staged coalesced
// epilogue for BOTH bf16 (32KB) and f32 (64KB) outputs.
__global__ __launch_bounds__(256) void k_gemm(const u16* __restrict__ Aagg,
                                              const u16* __restrict__ Ax,
                                              const u16* __restrict__ Wlt,
                                              const u16* __restrict__ Wrt,
                                              const float* __restrict__ bias,
                                              u16* __restrict__ ybf,
                                              float* __restrict__ yf,
                                              int do_relu) {
  // A0 [0,8192) A1 [8192,16384) B0 [16384,24576) B1 [24576,32768)  (u16 idx)
  __shared__ u16 sh[32768] __attribute__((aligned(16)));

  int tid = threadIdx.x;
  int w = tid >> 6, lane = tid & 63;
  int wr = w >> 1, wc = w & 1;
  int lr = lane & 15;
  int hi = lane >> 4;  // 0..3

  // XCD-bijective decode: same rowTile's 4 colTiles land consecutively on one XCD
  int lin = blockIdx.x;
  int xcd = lin & 7;
  int t = lin >> 3;
  int colT = t & 3;
  int rowT = (t >> 2) * 8 + xcd;  // 0..391
  int blockRow = rowT * 128;
  int nbase = colT * 128;

  // staging source pre-swizzle: LDS granule (row, posg) holds global granule posg^(row&7)
  int srow = lane >> 3;                 // row-within-segment 0..7 (== destRow&7)
  int scol = ((lane & 7) ^ srow) << 3;  // swizzled source column (elements)

  f32x4 acc[4][4];
#pragma unroll
  for (int m = 0; m < 4; ++m)
#pragma unroll
    for (int n = 0; n < 4; ++n) acc[m][n] = (f32x4){0.f, 0.f, 0.f, 0.f};

  // stage K-tile kt (0..15) into buffer b: 8 gload16 per thread
  auto stage = [&](int kt, int b) {
    const u16* Ap = (kt < 8) ? Aagg : Ax;
    const u16* Bp = (kt < 8) ? Wlt : Wrt;
    int kb = (kt & 7) << 6;
    u16* Ad = sh + b * 8192;
    u16* Bd = sh + 16384 + b * 8192;
#pragma unroll
    for (int i = 0; i < 4; ++i) {
      int s = (w << 2) + i;
      int ar = blockRow + s * 8 + srow;
      if (ar > NN - 1) ar = NN - 1;
      int br = nbase + s * 8 + srow;
      gload16(Ap + (size_t)ar * DD + kb + scol, Ad + s * 512);
      gload16(Bp + (size_t)br * DD + kb + scol, Bd + s * 512);
    }
  };

  auto compute = [&](int cur) {
    const u16* As = sh + cur * 8192;
    const u16* Bs = sh + 16384 + cur * 8192;
#pragma unroll
    for (int k2 = 0; k2 < 2; ++k2) {
      int gA = (k2 << 2) + hi;  // wanted k-granule 0..7
      bf16x8 af[4], bfr[4];
#pragma unroll
      for (int m = 0; m < 4; ++m) {
        int r = wr * 64 + m * 16 + lr;
        af[m] = *(const bf16x8*)(As + r * 64 + ((gA ^ (r & 7)) << 3));
      }
#pragma unroll
      for (int n = 0; n < 4; ++n) {
        int r = wc * 64 + n * 16 + lr;
        bfr[n] = *(const bf16x8*)(Bs + r * 64 + ((gA ^ (r & 7)) << 3));
      }
      __builtin_amdgcn_s_setprio(1);
#pragma unroll
      for (int m = 0; m < 4; ++m)
#pragma unroll
        for (int n = 0; n < 4; ++n)
          acc[m][n] = __builtin_amdgcn_mfma_f32_16x16x32_bf16(af[m], bfr[n], acc[m][n], 0, 0, 0);
      __builtin_amdgcn_s_setprio(0);
    }
  };

  stage(0, 0);
  stage(1, 1);  // 16 loads outstanding

  for (int kt = 0; kt < 15; ++kt) {
    int cur = kt & 1;
    // tile kt's 8 loads done; tile kt+1's 8 remain in flight
    asm volatile("s_waitcnt vmcnt(8)" ::: "memory");
    __builtin_amdgcn_s_barrier();
    compute(cur);
    __builtin_amdgcn_s_barrier();  // all waves done reading buf cur
    if (kt + 2 < 16) stage(kt + 2, cur);
  }
  // last tile: only its own 8 loads outstanding -> full drain
  asm volatile("s_waitcnt vmcnt(0)" ::: "memory");
  __builtin_amdgcn_s_barrier();
  compute(1);
  __builtin_amdgcn_s_barrier();

  if (yf) {
    // f32 output (final layer): stage 128x128 f32 C tile in sh (exactly 64KB),
    // then 512B-contiguous row writes (16 threads x 32B per row).
    float* shf = (float*)sh;
#pragma unroll
    for (int n = 0; n < 4; ++n) {
      int col = wc * 64 + n * 16 + lr;  // tile-local col
      float bv = bias[nbase + col];
#pragma unroll
      for (int m = 0; m < 4; ++m) {
        f32x4 v = acc[m][n];
#pragma unroll
        for (int r = 0; r < 4; ++r) {
          int rl = wr * 64 + m * 16 + hi * 4 + r;
          float y = v[r] + bv;
          if (do_relu) y = fmaxf(y, 0.f);
          shf[rl * 128 + col] = y;
        }
      }
    }
    __syncthreads();
#pragma unroll
    for (int p = 0; p < 8; ++p) {
      int rl = p * 16 + (tid >> 4);
      int grow = blockRow + rl;
      if (grow < NN) {
        const uint4* rowp = (const uint4*)(shf + rl * 128);
        int c = (tid & 15) * 2;
        uint4 v0 = rowp[c];
        uint4 v1 = rowp[c + 1];
        uint4* gp = (uint4*)(yf + (size_t)grow * DD + nbase);
        gp[c] = v0;
        gp[c + 1] = v1;
      }
    }
  } else {
    // bf16 output: stage C tile (128x128 u16 = 32KB in sh[0..16384)) then coalesced writes
#pragma unroll
    for (int n = 0; n < 4; ++n) {
      int col = nbase + wc * 64 + n * 16 + lr;
      float bv = bias[col];
      int g = wc * 8 + n * 2 + (lr >> 3);  // col granule 0..15
#pragma unroll
      for (int m = 0; m < 4; ++m) {
        f32x4 v = acc[m][n];
#pragma unroll
        for (int r = 0; r < 4; ++r) {
          int rl = wr * 64 + m * 16 + hi * 4 + r;
          float y = v[r] + bv;
          if (do_relu) y = fmaxf(y, 0.f);
          sh[rl * 128 + ((g ^ (rl & 15)) << 3) + (lr & 7)] = f2bf(y);
        }
      }
    }
    __syncthreads();
#pragma unroll
    for (int p = 0; p < 8; ++p) {
      int rl = p * 16 + (tid >> 4);
      int gg = tid & 15;
      int grow = blockRow + rl;
      if (grow < NN) {
        uint4 vv = *(const uint4*)(sh + rl * 128 + ((gg ^ (rl & 15)) << 3));
        *(uint4*)(ybf + (size_t)grow * DD + nbase + gg * 8) = vv;
      }
    }
  }
}

extern "C" void kernel_launch(void* const* d_in, const int* in_sizes, int n_in,
                              void* d_out, int out_size, void* d_ws, size_t ws_size,
                              hipStream_t stream) {
  const float* x_in = (const float*)d_in[0];
  const void* eidx = d_in[1];
  const float* Wl[3] = {(const float*)d_in[2], (const float*)d_in[5], (const float*)d_in[8]};
  const float* bl[3] = {(const float*)d_in[3], (const float*)d_in[6], (const float*)d_in[9]};
  const float* Wr[3] = {(const float*)d_in[4], (const float*)d_in[7], (const float*)d_in[10]};

  // workspace layout
  char* w = (char*)d_ws;
  auto alloc = [&](size_t bytes) {
    char* p = w;
    w += (bytes + 255) & ~(size_t)255;
    return p;
  };
  int* vio = (int*)alloc(4);
  int* deg = (int*)alloc((size_t)NN * 4);
  int* cursor = (int*)alloc((size_t)NN * 4);
  int* offs = (int*)alloc((size_t)(NN + 1) * 4);
  int* bsums = (int*)alloc(256 * 4);
  int* boffs = (int*)alloc(256 * 4);
  int* srcA = (int*)alloc((size_t)NE * 4);
  int* dstA = (int*)alloc((size_t)NE * 4);
  int* csr = (int*)alloc((size_t)NE * 4);
  float* invd = (float*)alloc((size_t)NN * 4);
  u16* wt = (u16*)alloc((size_t)6 * DD * DD * 2);
  u16* xb = (u16*)alloc((size_t)NN * DD * 2);
  u16* aggb = (u16*)alloc((size_t)NN * DD * 2);

  u16* wt0l = wt + 0 * DD * DD;
  u16* wt0r = wt + 1 * DD * DD;
  u16* wt1l = wt + 2 * DD * DD;
  u16* wt1r = wt + 3 * DD * DD;
  u16* wt2l = wt + 4 * DD * DD;
  u16* wt2r = wt + 5 * DD * DD;

  u16* dob = (u16*)d_out;  // bf16 scratch inside d_out (layer0 y / layer1 x)

  // zero vio/deg/cursor in one memset (contiguous at ws start)
  size_t zbytes = (size_t)((char*)offs - (char*)vio);
  hipMemsetAsync(vio, 0, zbytes, stream);

  k_detect<<<256, 256, 0, stream>>>((const long long*)eidx, vio);
  k_normcnt<<<512, 256, 0, stream>>>(eidx, vio, srcA, dstA, deg);
  k_scan1<<<NB, 256, 0, stream>>>(deg, offs, bsums);
  k_scan2<<<1, 256, 0, stream>>>(bsums, boffs);
  k_scan3<<<NB, 256, 0, stream>>>(offs, boffs, deg, invd);
  k_fill<<<(NE + 255) / 256, 256, 0, stream>>>(srcA, dstA, offs, cursor, csr);

  k_wt6<<<dim3(16, 16, 6), 256, 0, stream>>>(Wl[0], Wr[0], Wl[1], Wr[1], Wl[2], Wr[2], wt);
  k_cvt<<<(NN * DD / 8 + 255) / 256, 256, 0, stream>>>(x_in, xb);

  const int GEMM_GRID = 1568;  // 392 rowTiles x 4 colTiles, 8-divisible
  // layer 0: x = xb, y -> d_out (bf16)
  k_agg<<<(NN + 3) / 4, 256, 0, stream>>>(xb, offs, csr, invd, aggb);
  k_gemm<<<GEMM_GRID, 256, 0, stream>>>(aggb, xb, wt0l, wt0r, bl[0], dob, (float*)nullptr, 1);
  // layer 1: x = d_out (bf16), y -> xb
  k_agg<<<(NN + 3) / 4, 256, 0, stream>>>(dob, offs, csr, invd, aggb);
  k_gemm<<<GEMM_GRID, 256, 0, stream>>>(aggb, dob, wt1l, wt1r, bl[1], xb, (float*)nullptr, 1);
  // layer 2: x = xb, y -> d_out (f32, no relu)
  k_agg<<<(NN + 3) / 4, 256, 0, stream>>>(xb, offs, csr, invd, aggb);
  k_gemm<<<GEMM_GRID, 256, 0, stream>>>(aggb, xb, wt2l, wt2r, bl[2], (u16*)nullptr, (float*)d_out, 0);

  (void)in_sizes; (void)n_in; (void)out_size; (void)ws_size;
}

// Round 10
// 467.420 us; speedup vs baseline: 2.1591x; 1.0018x over previous
//
#include <hip/hip_runtime.h>

#define NN 50000
#define NE 400000
#define DD 512
#define NB 196  // ceil(NN/256)

typedef unsigned short u16;
typedef float f32x4 __attribute__((ext_vector_type(4)));
typedef __bf16 bf16x8 __attribute__((ext_vector_type(8)));

__device__ __forceinline__ u16 f2bf(float f) {
  unsigned u = __builtin_bit_cast(unsigned, f);
  unsigned r = (u + 0x7FFFu + ((u >> 16) & 1u)) >> 16;
  return (u16)r;
}
__device__ __forceinline__ float bf_lo(unsigned v) {
  return __builtin_bit_cast(float, v << 16);
}
__device__ __forceinline__ float bf_hi(unsigned v) {
  return __builtin_bit_cast(float, v & 0xffff0000u);
}

__device__ __forceinline__ void gload16(const void* g, void* l) {
  __builtin_amdgcn_global_load_lds(
      (const __attribute__((address_space(1))) unsigned int*)g,
      (__attribute__((address_space(3))) unsigned int*)l, 16, 0, 0);
}

// ---------- edge dtype detect ----------
__global__ void k_detect(const long long* __restrict__ p, int* __restrict__ vio) {
  bool bad = false;
  for (int i = blockIdx.x * blockDim.x + threadIdx.x; i < NE; i += blockDim.x * gridDim.x) {
    long long v = p[i];
    bad |= (v < 0 || v >= NN);
  }
  unsigned long long m = __ballot(bad);
  if (m != 0ull && (threadIdx.x & 63) == 0) atomicOr(vio, 1);
}

// ---------- normalize edges + degree count (fused) ----------
__global__ void k_normcnt(const void* __restrict__ ep, const int* __restrict__ vio,
                          int* __restrict__ src, int* __restrict__ dst,
                          int* __restrict__ deg) {
  bool is64 = (*vio == 0);
  for (int e = blockIdx.x * blockDim.x + threadIdx.x; e < NE; e += blockDim.x * gridDim.x) {
    int s_, d_;
    if (is64) {
      const long long* p = (const long long*)ep;
      s_ = (int)p[e];
      d_ = (int)p[NE + e];
    } else {
      const int* p = (const int*)ep;
      s_ = p[e];
      d_ = p[NE + e];
    }
    src[e] = s_;
    dst[e] = d_;
    atomicAdd(&deg[d_], 1);
  }
}

// ---------- scan / CSR ----------
__global__ void k_scan1(const int* __restrict__ deg, int* __restrict__ offs,
                        int* __restrict__ bsums) {
  __shared__ int sm[256];
  int t = threadIdx.x, i = blockIdx.x * 256 + t;
  int v = (i < NN) ? deg[i] : 0;
  sm[t] = v;
  __syncthreads();
  int x = v;
  for (int d = 1; d < 256; d <<= 1) {
    int y = (t >= d) ? sm[t - d] : 0;
    __syncthreads();
    x += y;
    sm[t] = x;
    __syncthreads();
  }
  if (i < NN) offs[i + 1] = x;
  if (t == 255) bsums[blockIdx.x] = x;
}

// scan2 folded in: each block reduces bsums[0..bid) itself (196 ints, trivial)
__global__ void k_scan3(int* __restrict__ offs, const int* __restrict__ bsums,
                        const int* __restrict__ deg, float* __restrict__ invd) {
  __shared__ int ws[4];
  int bid = blockIdx.x, t = threadIdx.x;
  int v = (t < bid) ? bsums[t] : 0;  // bid <= 195 < 256
  v += __shfl_down(v, 32);
  v += __shfl_down(v, 16);
  v += __shfl_down(v, 8);
  v += __shfl_down(v, 4);
  v += __shfl_down(v, 2);
  v += __shfl_down(v, 1);
  if ((t & 63) == 0) ws[t >> 6] = v;
  __syncthreads();
  int prefix = ws[0] + ws[1] + ws[2] + ws[3];
  int i = bid * 256 + t;
  if (i == 0) offs[0] = 0;
  if (i < NN) {
    offs[i + 1] += prefix;
    int dg = deg[i];
    if (dg < 1) dg = 1;
    invd[i] = 1.0f / (float)dg;
  }
}

__global__ void k_fill(const int* __restrict__ src, const int* __restrict__ dst,
                       const int* __restrict__ offs, int* __restrict__ cursor,
                       int* __restrict__ csr) {
  int e = blockIdx.x * 256 + threadIdx.x;
  if (e < NE) {
    int d = dst[e];
    int p = atomicAdd(&cursor[d], 1);
    csr[offs[d] + p] = src[e];
  }
}

// ---------- all-6 weight transpose + bf16 convert (one dispatch) ----------
__global__ void k_wt6(const float* __restrict__ W0, const float* __restrict__ W1,
                      const float* __restrict__ W2, const float* __restrict__ W3,
                      const float* __restrict__ W4, const float* __restrict__ W5,
                      u16* __restrict__ wt) {
  __shared__ float t[32][33];
  const float* W;
  switch (blockIdx.z) {
    case 0: W = W0; break;
    case 1: W = W1; break;
    case 2: W = W2; break;
    case 3: W = W3; break;
    case 4: W = W4; break;
    default: W = W5; break;
  }
  u16* Wt = wt + (size_t)blockIdx.z * DD * DD;
  int tx = threadIdx.x & 31, ty = threadIdx.x >> 5;  // 32x8
  int bx = blockIdx.x, by = blockIdx.y;
#pragma unroll
  for (int i = 0; i < 32; i += 8)
    t[ty + i][tx] = W[(size_t)(bx * 32 + ty + i) * DD + by * 32 + tx];
  __syncthreads();
#pragma unroll
  for (int i = 0; i < 32; i += 8)
    Wt[(size_t)(by * 32 + ty + i) * DD + bx * 32 + tx] = f2bf(t[tx][ty + i]);
}

// ---------- x f32 -> bf16 ----------
__global__ void k_cvt(const float* __restrict__ x, u16* __restrict__ xb) {
  size_t i = (size_t)(blockIdx.x * 256 + threadIdx.x) * 8;
  float4 a = *(const float4*)(x + i);
  float4 b = *(const float4*)(x + i + 4);
  uint4 o;
  o.x = (unsigned)f2bf(a.x) | ((unsigned)f2bf(a.y) << 16);
  o.y = (unsigned)f2bf(a.z) | ((unsigned)f2bf(a.w) << 16);
  o.z = (unsigned)f2bf(b.x) | ((unsigned)f2bf(b.y) << 16);
  o.w = (unsigned)f2bf(b.z) | ((unsigned)f2bf(b.w) << 16);
  *(uint4*)(xb + i) = o;
}

#define ACC8(V)                                                     \
  a0 += bf_lo(V.x); a1 += bf_hi(V.x); a2 += bf_lo(V.y); a3 += bf_hi(V.y); \
  a4 += bf_lo(V.z); a5 += bf_hi(V.z); a6 += bf_lo(V.w); a7 += bf_hi(V.w);

// ---------- aggregation: one wave per node, 8-deep load pipeline ----------
// (R7-validated: whole 1KB rows, L3-resident gather; ~50us/dispatch = ~9TB/s
// effective L3-fabric gather -- at floor for random-graph pull aggregation)
__global__ __launch_bounds__(256) void k_agg(const u16* __restrict__ xb,
                                             const int* __restrict__ offs,
                                             const int* __restrict__ csr,
                                             const float* __restrict__ invd,
                                             u16* __restrict__ agg) {
  int node = blockIdx.x * 4 + (threadIdx.x >> 6);
  int lane = threadIdx.x & 63;
  if (node >= NN) return;
  int s = offs[node], e = offs[node + 1];
  float a0 = 0, a1 = 0, a2 = 0, a3 = 0, a4 = 0, a5 = 0, a6 = 0, a7 = 0;
  int j = s;
  for (; j + 8 <= e; j += 8) {
    int u0 = csr[j], u1 = csr[j + 1], u2 = csr[j + 2], u3 = csr[j + 3];
    int u4 = csr[j + 4], u5 = csr[j + 5], u6 = csr[j + 6], u7 = csr[j + 7];
    uint4 v0 = *(const uint4*)(xb + (size_t)u0 * DD + lane * 8);
    uint4 v1 = *(const uint4*)(xb + (size_t)u1 * DD + lane * 8);
    uint4 v2 = *(const uint4*)(xb + (size_t)u2 * DD + lane * 8);
    uint4 v3 = *(const uint4*)(xb + (size_t)u3 * DD + lane * 8);
    uint4 v4 = *(const uint4*)(xb + (size_t)u4 * DD + lane * 8);
    uint4 v5 = *(const uint4*)(xb + (size_t)u5 * DD + lane * 8);
    uint4 v6 = *(const uint4*)(xb + (size_t)u6 * DD + lane * 8);
    uint4 v7 = *(const uint4*)(xb + (size_t)u7 * DD + lane * 8);
    ACC8(v0) ACC8(v1) ACC8(v2) ACC8(v3) ACC8(v4) ACC8(v5) ACC8(v6) ACC8(v7)
  }
  for (; j + 4 <= e; j += 4) {
    int u0 = csr[j], u1 = csr[j + 1], u2 = csr[j + 2], u3 = csr[j + 3];
    uint4 v0 = *(const uint4*)(xb + (size_t)u0 * DD + lane * 8);
    uint4 v1 = *(const uint4*)(xb + (size_t)u1 * DD + lane * 8);
    uint4 v2 = *(const uint4*)(xb + (size_t)u2 * DD + lane * 8);
    uint4 v3 = *(const uint4*)(xb + (size_t)u3 * DD + lane * 8);
    ACC8(v0) ACC8(v1) ACC8(v2) ACC8(v3)
  }
  for (; j < e; ++j) {
    int u = csr[j];
    uint4 v = *(const uint4*)(xb + (size_t)u * DD + lane * 8);
    ACC8(v)
  }
  float sc = invd[node];
  uint4 o;
  o.x = (unsigned)f2bf(a0 * sc) | ((unsigned)f2bf(a1 * sc) << 16);
  o.y = (unsigned)f2bf(a2 * sc) | ((unsigned)f2bf(a3 * sc) << 16);
  o.z = (unsigned)f2bf(a4 * sc) | ((unsigned)f2bf(a5 * sc) << 16);
  o.w = (unsigned)f2bf(a6 * sc) | ((unsigned)f2bf(a7 * sc) << 16);
  *(uint4*)(agg + (size_t)node * DD + lane * 8) = o;
}

// ---------- fused GEMM: C = relu?(Agg@Wl + X@Wr + b) ----------
// R4/R9 structure (best measured): BM=128, BN=128, BK=64, 4 waves (2x2),
// 2-deep counted-vmcnt pipeline; XOR-swizzled LDS (0 conflicts);
// XCD-bijective grid swizzle; setprio around MFMAs; LDS-staged coalesced
// epilogue for BOTH bf16 (32KB) and f32 (64KB, granule^rl&7 swizzled).
__global__ __launch_bounds__(256) void k_gemm(const u16* __restrict__ Aagg,
                                              const u16* __restrict__ Ax,
                                              const u16* __restrict__ Wlt,
                                              const u16* __restrict__ Wrt,
                                              const float* __restrict__ bias,
                                              u16* __restrict__ ybf,
                                              float* __restrict__ yf,
                                              int do_relu) {
  // A0 [0,8192) A1 [8192,16384) B0 [16384,24576) B1 [24576,32768)  (u16 idx)
  __shared__ u16 sh[32768] __attribute__((aligned(16)));

  int tid = threadIdx.x;
  int w = tid >> 6, lane = tid & 63;
  int wr = w >> 1, wc = w & 1;
  int lr = lane & 15;
  int hi = lane >> 4;  // 0..3

  // XCD-bijective decode: same rowTile's 4 colTiles land consecutively on one XCD
  int lin = blockIdx.x;
  int xcd = lin & 7;
  int t = lin >> 3;
  int colT = t & 3;
  int rowT = (t >> 2) * 8 + xcd;  // 0..391
  int blockRow = rowT * 128;
  int nbase = colT * 128;

  // staging source pre-swizzle: LDS granule (row, posg) holds global granule posg^(row&7)
  int srow = lane >> 3;                 // row-within-segment 0..7 (== destRow&7)
  int scol = ((lane & 7) ^ srow) << 3;  // swizzled source column (elements)

  f32x4 acc[4][4];
#pragma unroll
  for (int m = 0; m < 4; ++m)
#pragma unroll
    for (int n = 0; n < 4; ++n) acc[m][n] = (f32x4){0.f, 0.f, 0.f, 0.f};

  // stage K-tile kt (0..15) into buffer b: 8 gload16 per thread
  auto stage = [&](int kt, int b) {
    const u16* Ap = (kt < 8) ? Aagg : Ax;
    const u16* Bp = (kt < 8) ? Wlt : Wrt;
    int kb = (kt & 7) << 6;
    u16* Ad = sh + b * 8192;
    u16* Bd = sh + 16384 + b * 8192;
#pragma unroll
    for (int i = 0; i < 4; ++i) {
      int s = (w << 2) + i;
      int ar = blockRow + s * 8 + srow;
      if (ar > NN - 1) ar = NN - 1;
      int br = nbase + s * 8 + srow;
      gload16(Ap + (size_t)ar * DD + kb + scol, Ad + s * 512);
      gload16(Bp + (size_t)br * DD + kb + scol, Bd + s * 512);
    }
  };

  auto compute = [&](int cur) {
    const u16* As = sh + cur * 8192;
    const u16* Bs = sh + 16384 + cur * 8192;
#pragma unroll
    for (int k2 = 0; k2 < 2; ++k2) {
      int gA = (k2 << 2) + hi;  // wanted k-granule 0..7
      bf16x8 af[4], bfr[4];
#pragma unroll
      for (int m = 0; m < 4; ++m) {
        int r = wr * 64 + m * 16 + lr;
        af[m] = *(const bf16x8*)(As + r * 64 + ((gA ^ (r & 7)) << 3));
      }
#pragma unroll
      for (int n = 0; n < 4; ++n) {
        int r = wc * 64 + n * 16 + lr;
        bfr[n] = *(const bf16x8*)(Bs + r * 64 + ((gA ^ (r & 7)) << 3));
      }
      __builtin_amdgcn_s_setprio(1);
#pragma unroll
      for (int m = 0; m < 4; ++m)
#pragma unroll
        for (int n = 0; n < 4; ++n)
          acc[m][n] = __builtin_amdgcn_mfma_f32_16x16x32_bf16(af[m], bfr[n], acc[m][n], 0, 0, 0);
      __builtin_amdgcn_s_setprio(0);
    }
  };

  stage(0, 0);
  stage(1, 1);  // 16 loads outstanding

  for (int kt = 0; kt < 15; ++kt) {
    int cur = kt & 1;
    // tile kt's 8 loads done; tile kt+1's 8 remain in flight
    asm volatile("s_waitcnt vmcnt(8)" ::: "memory");
    __builtin_amdgcn_s_barrier();
    compute(cur);
    __builtin_amdgcn_s_barrier();  // all waves done reading buf cur
    if (kt + 2 < 16) stage(kt + 2, cur);
  }
  // last tile: only its own 8 loads outstanding -> full drain
  asm volatile("s_waitcnt vmcnt(0)" ::: "memory");
  __builtin_amdgcn_s_barrier();
  compute(1);
  __builtin_amdgcn_s_barrier();

  if (yf) {
    // f32 output (final layer): stage 128x128 f32 C tile in sh (exactly 64KB),
    // 16B granules swizzled by G ^ (rl&7); then 512B-contiguous row writes.
    float* shf = (float*)sh;
#pragma unroll
    for (int n = 0; n < 4; ++n) {
      int col = wc * 64 + n * 16 + lr;  // tile-local col
      float bv = bias[nbase + col];
      int gf = col >> 2;                // 16B granule 0..31
      int ci = col & 3;
#pragma unroll
      for (int m = 0; m < 4; ++m) {
        f32x4 v = acc[m][n];
#pragma unroll
        for (int r = 0; r < 4; ++r) {
          int rl = wr * 64 + m * 16 + hi * 4 + r;
          float y = v[r] + bv;
          if (do_relu) y = fmaxf(y, 0.f);
          shf[rl * 128 + ((gf ^ (rl & 7)) << 2) + ci] = y;
        }
      }
    }
    __syncthreads();
#pragma unroll
    for (int p = 0; p < 8; ++p) {
      int rl = p * 16 + (tid >> 4);
      int grow = blockRow + rl;
      if (grow < NN) {
        int gg = (tid & 15) * 2;  // output granule pair
        uint4 v0 = *(const uint4*)(shf + rl * 128 + (((gg) ^ (rl & 7)) << 2));
        uint4 v1 = *(const uint4*)(shf + rl * 128 + (((gg + 1) ^ (rl & 7)) << 2));
        uint4* gp = (uint4*)(yf + (size_t)grow * DD + nbase);
        gp[gg] = v0;
        gp[gg + 1] = v1;
      }
    }
  } else {
    // bf16 output: stage C tile (128x128 u16 = 32KB in sh[0..16384)) then coalesced writes
#pragma unroll
    for (int n = 0; n < 4; ++n) {
      int col = nbase + wc * 64 + n * 16 + lr;
      float bv = bias[col];
      int g = wc * 8 + n * 2 + (lr >> 3);  // col granule 0..15
#pragma unroll
      for (int m = 0; m < 4; ++m) {
        f32x4 v = acc[m][n];
#pragma unroll
        for (int r = 0; r < 4; ++r) {
          int rl = wr * 64 + m * 16 + hi * 4 + r;
          float y = v[r] + bv;
          if (do_relu) y = fmaxf(y, 0.f);
          sh[rl * 128 + ((g ^ (rl & 15)) << 3) + (lr & 7)] = f2bf(y);
        }
      }
    }
    __syncthreads();
#pragma unroll
    for (int p = 0; p < 8; ++p) {
      int rl = p * 16 + (tid >> 4);
      int gg = tid & 15;
      int grow = blockRow + rl;
      if (grow < NN) {
        uint4 vv = *(const uint4*)(sh + rl * 128 + ((gg ^ (rl & 15)) << 3));
        *(uint4*)(ybf + (size_t)grow * DD + nbase + gg * 8) = vv;
      }
    }
  }
}

extern "C" void kernel_launch(void* const* d_in, const int* in_sizes, int n_in,
                              void* d_out, int out_size, void* d_ws, size_t ws_size,
                              hipStream_t stream) {
  const float* x_in = (const float*)d_in[0];
  const void* eidx = d_in[1];
  const float* Wl[3] = {(const float*)d_in[2], (const float*)d_in[5], (const float*)d_in[8]};
  const float* bl[3] = {(const float*)d_in[3], (const float*)d_in[6], (const float*)d_in[9]};
  const float* Wr[3] = {(const float*)d_in[4], (const float*)d_in[7], (const float*)d_in[10]};

  // workspace layout
  char* w = (char*)d_ws;
  auto alloc = [&](size_t bytes) {
    char* p = w;
    w += (bytes + 255) & ~(size_t)255;
    return p;
  };
  int* vio = (int*)alloc(4);
  int* deg = (int*)alloc((size_t)NN * 4);
  int* cursor = (int*)alloc((size_t)NN * 4);
  int* offs = (int*)alloc((size_t)(NN + 1) * 4);
  int* bsums = (int*)alloc(256 * 4);
  int* boffs = (int*)alloc(256 * 4);
  int* srcA = (int*)alloc((size_t)NE * 4);
  int* dstA = (int*)alloc((size_t)NE * 4);
  int* csr = (int*)alloc((size_t)NE * 4);
  float* invd = (float*)alloc((size_t)NN * 4);
  u16* wt = (u16*)alloc((size_t)6 * DD * DD * 2);
  u16* xb = (u16*)alloc((size_t)NN * DD * 2);
  u16* aggb = (u16*)alloc((size_t)NN * DD * 2);

  u16* wt0l = wt + 0 * DD * DD;
  u16* wt0r = wt + 1 * DD * DD;
  u16* wt1l = wt + 2 * DD * DD;
  u16* wt1r = wt + 3 * DD * DD;
  u16* wt2l = wt + 4 * DD * DD;
  u16* wt2r = wt + 5 * DD * DD;

  u16* dob = (u16*)d_out;  // bf16 scratch inside d_out (layer0 y / layer1 x)

  // zero vio/deg/cursor in one memset (contiguous at ws start)
  size_t zbytes = (size_t)((char*)offs - (char*)vio);
  hipMemsetAsync(vio, 0, zbytes, stream);

  k_detect<<<256, 256, 0, stream>>>((const long long*)eidx, vio);
  k_normcnt<<<512, 256, 0, stream>>>(eidx, vio, srcA, dstA, deg);
  k_scan1<<<NB, 256, 0, stream>>>(deg, offs, bsums);
  k_scan3<<<NB, 256, 0, stream>>>(offs, bsums, deg, invd);
  k_fill<<<(NE + 255) / 256, 256, 0, stream>>>(srcA, dstA, offs, cursor, csr);

  k_wt6<<<dim3(16, 16, 6), 256, 0, stream>>>(Wl[0], Wr[0], Wl[1], Wr[1], Wl[2], Wr[2], wt);
  k_cvt<<<(NN * DD / 8 + 255) / 256, 256, 0, stream>>>(x_in, xb);

  const int GEMM_GRID = 1568;  // 392 rowTiles x 4 colTiles, 8-divisible
  // layer 0: x = xb, y -> d_out (bf16)
  k_agg<<<(NN + 3) / 4, 256, 0, stream>>>(xb, offs, csr, invd, aggb);
  k_gemm<<<GEMM_GRID, 256, 0, stream>>>(aggb, xb, wt0l, wt0r, bl[0], dob, (float*)nullptr, 1);
  // layer 1: x = d_out (bf16), y -> xb
  k_agg<<<(NN + 3) / 4, 256, 0, stream>>>(dob, offs, csr, invd, aggb);
  k_gemm<<<GEMM_GRID, 256, 0, stream>>>(aggb, dob, wt1l, wt1r, bl[1], xb, (float*)nullptr, 1);
  // layer 2: x = xb, y -> d_out (f32, no relu)
  k_agg<<<(NN + 3) / 4, 256, 0, stream>>>(xb, offs, csr, invd, aggb);
  k_gemm<<<GEMM_GRID, 256, 0, stream>>>(aggb, xb, wt2l, wt2r, bl[2], (u16*)nullptr, (float*)d_out, 0);

  (void)boffs;
  (void)in_sizes; (void)n_in; (void)out_size; (void)ws_size;
}